// Round 4
// baseline (171.626 us; speedup 1.0000x reference)
//
#include <hip/hip_runtime.h>

typedef float v4f __attribute__((ext_vector_type(4)));
typedef int   v4i __attribute__((ext_vector_type(4)));

#define BB 512
#define CC 3
#define TT 16384
#define NBLK 2048
#define NTHREADS (NBLK * 256)          // 524288 threads
#define NQUAD (BB * TT / 4)            // 2,097,152 quads
#define ITERS (NQUAD / NTHREADS)       // 4 quads per thread
// partials (SoA in d_ws): [0..2047]=nll, [2048..4095]=ss, [4096..6143]=cnt
// penalized transitions (prev,next) in {(0,2),(2,1),(1,0)} -> 3*p+n in {2,7,3} -> mask 0x8C

__global__ __launch_bounds__(256) void ce_trans_main(const float* __restrict__ logits,
                                                     const int* __restrict__ labels,
                                                     float* __restrict__ partials) {
    const int tid0 = blockIdx.x * 256 + threadIdx.x;
    const int lane = threadIdx.x & 63;

    float nll = 0.f, ss = 0.f;
    int cnt = 0;

    // 2-deep software pipeline state (plain cached loads — nt hurt: it defeated
    // L1/L2 service of the lane-63 boundary re-reads and buys nothing for one-pass streams)
    v4f A[2], Bv[2], Cv[2];
    v4i Lv[2];
    int TQ[2];
    const float* P0[2];

    auto issue = [&](int it, int slot) {
        const int q  = it * NTHREADS + tid0;
        const int b  = q >> 12;          // 4096 quads per (b) row
        const int tq = q & 4095;
        const float* p0 = logits + (size_t)b * (CC * TT) + (tq << 2);
        A[slot]  = *reinterpret_cast<const v4f*>(p0);
        Bv[slot] = *reinterpret_cast<const v4f*>(p0 + TT);
        Cv[slot] = *reinterpret_cast<const v4f*>(p0 + 2 * TT);
        Lv[slot] = *reinterpret_cast<const v4i*>(labels + (size_t)b * TT + (tq << 2));
        TQ[slot] = tq;
        P0[slot] = p0;
    };

    auto compute = [&](int slot) {
        const v4f a = A[slot], bq = Bv[slot], c = Cv[slot];
        const v4i l = Lv[slot];
        const float x0[4] = {a.x,  a.y,  a.z,  a.w};
        const float x1[4] = {bq.x, bq.y, bq.z, bq.w};
        const float x2[4] = {c.x,  c.y,  c.z,  c.w};
        const int  lab[4] = {l.x,  l.y,  l.z,  l.w};
        int am[4];

#pragma unroll
        for (int j = 0; j < 4; ++j) {
            const float v0 = x0[j], v1 = x1[j], v2 = x2[j];
            int idx = 0;
            float mx = v0;
            if (v1 > mx) { mx = v1; idx = 1; }   // strict > == first-occurrence argmax
            if (v2 > mx) { mx = v2; idx = 2; }
            am[j] = idx;
            const float e  = __expf(v0 - mx) + __expf(v1 - mx) + __expf(v2 - mx);
            const float xl = (lab[j] == 0) ? v0 : ((lab[j] == 1) ? v1 : v2);
            nll += mx + __logf(e) - xl;
        }

#pragma unroll
        for (int j = 0; j < 3; ++j) {
            const float d0 = x0[j + 1] - x0[j];
            const float d1 = x1[j + 1] - x1[j];
            const float d2 = x2[j + 1] - x2[j];
            ss += d0 * d0 + d1 * d1 + d2 * d2;
            cnt += (0x8C >> (3 * am[j] + am[j + 1])) & 1;
        }

        // boundary element t0+4 = neighbor lane's first element (waves never straddle rows:
        // one row = 4096 quads = 64 full waves)
        float xn0 = __shfl_down(x0[0], 1, 64);
        float xn1 = __shfl_down(x1[0], 1, 64);
        float xn2 = __shfl_down(x2[0], 1, 64);
        int   amn = __shfl_down(am[0], 1, 64);
        bool valid = true;
        if (lane == 63) {
            if (TQ[slot] == 4095) {
                valid = false;                    // row end: no t+1 neighbor
            } else {
                const float* p0 = P0[slot];
                xn0 = p0[4]; xn1 = p0[TT + 4]; xn2 = p0[2 * TT + 4];
                int idx = 0;
                float mx = xn0;
                if (xn1 > mx) { mx = xn1; idx = 1; }
                if (xn2 > mx) { mx = xn2; idx = 2; }
                amn = idx;
            }
        }
        if (valid) {
            const float d0 = xn0 - x0[3];
            const float d1 = xn1 - x1[3];
            const float d2 = xn2 - x2[3];
            ss += d0 * d0 + d1 * d1 + d2 * d2;
            cnt += (0x8C >> (3 * am[3] + amn)) & 1;
        }
    };

    issue(0, 0);
#pragma unroll
    for (int it = 0; it < ITERS; ++it) {
        if (it + 1 < ITERS) issue(it + 1, (it + 1) & 1);
        compute(it & 1);
    }

    // wave64 shuffle reduction
    float fcnt = (float)cnt;
#pragma unroll
    for (int off = 32; off > 0; off >>= 1) {
        nll  += __shfl_down(nll,  off, 64);
        ss   += __shfl_down(ss,   off, 64);
        fcnt += __shfl_down(fcnt, off, 64);
    }

    __shared__ float s_nll[4], s_ss[4], s_cnt[4];
    const int wave = threadIdx.x >> 6;
    if ((threadIdx.x & 63) == 0) { s_nll[wave] = nll; s_ss[wave] = ss; s_cnt[wave] = fcnt; }
    __syncthreads();
    if (threadIdx.x == 0) {
        partials[blockIdx.x]            = s_nll[0] + s_nll[1] + s_nll[2] + s_nll[3];
        partials[NBLK + blockIdx.x]     = s_ss[0]  + s_ss[1]  + s_ss[2]  + s_ss[3];
        partials[2 * NBLK + blockIdx.x] = s_cnt[0] + s_cnt[1] + s_cnt[2] + s_cnt[3];
    }
}

__global__ __launch_bounds__(256) void ce_trans_final(const float* __restrict__ partials,
                                                      float* __restrict__ out) {
    float sn = 0.f, st = 0.f, sc = 0.f;
    // each stream: 2048 floats = 512 float4; 256 threads x 2 float4
#pragma unroll
    for (int k = 0; k < 2; ++k) {
        const int i = k * 256 + threadIdx.x;
        const v4f n4 = *((const v4f*)partials + i);
        const v4f s4 = *((const v4f*)partials + 512 + i);
        const v4f c4 = *((const v4f*)partials + 1024 + i);
        sn += n4.x + n4.y + n4.z + n4.w;
        st += s4.x + s4.y + s4.z + s4.w;
        sc += c4.x + c4.y + c4.z + c4.w;
    }
#pragma unroll
    for (int off = 32; off > 0; off >>= 1) {
        sn += __shfl_down(sn, off, 64);
        st += __shfl_down(st, off, 64);
        sc += __shfl_down(sc, off, 64);
    }
    __shared__ float s_n[4], s_s[4], s_c[4];
    const int wave = threadIdx.x >> 6;
    if ((threadIdx.x & 63) == 0) { s_n[wave] = sn; s_s[wave] = st; s_c[wave] = sc; }
    __syncthreads();
    if (threadIdx.x == 0) {
        const float tn = s_n[0] + s_n[1] + s_n[2] + s_n[3];
        const float ts = s_s[0] + s_s[1] + s_s[2] + s_s[3];
        const float tc = s_c[0] + s_c[1] + s_c[2] + s_c[3];
        const float ce = tn / 8388608.0f;              // B*T
        const float sm = 0.01f * (ts / 25164288.0f);   // B*C*(T-1)
        const float tp = (tc > 0.5f) ? 0.1f : 0.0f;    // all table values are 1 => sum/count == 1
        out[0] = ce + sm + tp;
    }
}

extern "C" void kernel_launch(void* const* d_in, const int* in_sizes, int n_in,
                              void* d_out, int out_size, void* d_ws, size_t ws_size,
                              hipStream_t stream) {
    const float* logits = (const float*)d_in[0];
    const int*   labels = (const int*)d_in[1];
    float* out      = (float*)d_out;
    float* partials = (float*)d_ws;   // 3 * 2048 floats = 24 KB

    ce_trans_main<<<NBLK, 256, 0, stream>>>(logits, labels, partials);
    ce_trans_final<<<1, 256, 0, stream>>>(partials, out);
}

// Round 5
// 170.394 us; speedup vs baseline: 1.0072x; 1.0072x over previous
//
#include <hip/hip_runtime.h>

typedef float v4f __attribute__((ext_vector_type(4)));
typedef int   v4i __attribute__((ext_vector_type(4)));

#define BB 512
#define CC 3
#define TT 16384
#define ROW3 (CC * TT)                 // 49152 floats per batch row of logits
#define NBLK 4096
// Wave-centric single pass: 4096 blocks x 4 waves = 16384 waves; each wave owns
// 512 consecutive t of one row (two 256-t segments, quad A and quad C per lane).
// 32 waves per row => waves never straddle rows. No grid-stride loop: all 8 loads
// per thread issue back-to-back, then one compute, then retire.
// partials (SoA in d_ws): [0..4095]=nll, [4096..8191]=ss, [8192..12287]=cnt (48 KB)
// penalized transitions (prev,next) in {(0,2),(2,1),(1,0)} -> 3*p+n in {2,7,3} -> mask 0x8C

__device__ __forceinline__ int argmax3(float v0, float v1, float v2) {
    int idx = 0;
    float mx = v0;
    if (v1 > mx) { mx = v1; idx = 1; }   // strict > == first-occurrence argmax
    if (v2 > mx) { mx = v2; idx = 2; }
    return idx;
}

__global__ __launch_bounds__(256) void ce_trans_main(const float* __restrict__ logits,
                                                     const int* __restrict__ labels,
                                                     float* __restrict__ partials) {
    const int tid  = blockIdx.x * 256 + threadIdx.x;
    const int lane = threadIdx.x & 63;
    const int gw   = tid >> 6;           // global wave id
    const int b    = gw >> 5;            // 32 waves per row
    const int seg  = gw & 31;
    const int tb   = seg << 9;           // wave's t base (512 t per wave)

    const float* base = logits + (size_t)b * ROW3;
    const float* pA   = base + tb + 4 * lane;
    const int*   lp   = labels + (size_t)b * TT + tb + 4 * lane;

    // all 8 loads issue with no intervening dependent work
    const v4f a0 = *(const v4f*)pA;
    const v4f a1 = *(const v4f*)(pA + TT);
    const v4f a2 = *(const v4f*)(pA + 2 * TT);
    const v4i la = *(const v4i*)lp;
    const v4f c0 = *(const v4f*)(pA + 256);
    const v4f c1 = *(const v4f*)(pA + 256 + TT);
    const v4f c2 = *(const v4f*)(pA + 256 + 2 * TT);
    const v4i lc = *(const v4i*)(lp + 256);

    float nll = 0.f, ss = 0.f;
    int cnt = 0;
    int amA[4], amC[4];

    auto doquad = [&](const v4f& q0, const v4f& q1, const v4f& q2, const v4i& ql, int am[4]) {
        const float x0[4] = {q0.x, q0.y, q0.z, q0.w};
        const float x1[4] = {q1.x, q1.y, q1.z, q1.w};
        const float x2[4] = {q2.x, q2.y, q2.z, q2.w};
        const int  lab[4] = {ql.x, ql.y, ql.z, ql.w};
#pragma unroll
        for (int j = 0; j < 4; ++j) {
            const float v0 = x0[j], v1 = x1[j], v2 = x2[j];
            int idx = 0;
            float mx = v0;
            if (v1 > mx) { mx = v1; idx = 1; }
            if (v2 > mx) { mx = v2; idx = 2; }
            am[j] = idx;
            const float e  = __expf(v0 - mx) + __expf(v1 - mx) + __expf(v2 - mx);
            const float xl = (lab[j] == 0) ? v0 : ((lab[j] == 1) ? v1 : v2);
            nll += mx + __logf(e) - xl;
        }
#pragma unroll
        for (int j = 0; j < 3; ++j) {
            const float d0 = x0[j + 1] - x0[j];
            const float d1 = x1[j + 1] - x1[j];
            const float d2 = x2[j + 1] - x2[j];
            ss += d0 * d0 + d1 * d1 + d2 * d2;
            cnt += (0x8C >> (3 * am[j] + am[j + 1])) & 1;
        }
    };

    doquad(a0, a1, a2, la, amA);
    doquad(c0, c1, c2, lc, amC);

    // boundary after quad A (t = tb + 4*lane + 3 -> +4): neighbor lane's A-first;
    // lane 63's neighbor is quad C lane 0 (tb+256) — in-register broadcast, no load.
    {
        float n0 = __shfl_down(a0.x, 1, 64);
        float n1 = __shfl_down(a1.x, 1, 64);
        float n2 = __shfl_down(a2.x, 1, 64);
        int  nam = __shfl_down(amA[0], 1, 64);
        const float f0 = __shfl(c0.x, 0, 64);
        const float f1 = __shfl(c1.x, 0, 64);
        const float f2 = __shfl(c2.x, 0, 64);
        const int  fam = __shfl(amC[0], 0, 64);
        if (lane == 63) { n0 = f0; n1 = f1; n2 = f2; nam = fam; }
        const float d0 = n0 - a0.w, d1 = n1 - a1.w, d2 = n2 - a2.w;
        ss  += d0 * d0 + d1 * d1 + d2 * d2;
        cnt += (0x8C >> (3 * amA[3] + nam)) & 1;
    }
    // boundary after quad C: neighbor lane's C-first; lane 63 needs next segment's
    // first element (scalar loads, L1/L2-resident) unless this is the row end.
    {
        float n0 = __shfl_down(c0.x, 1, 64);
        float n1 = __shfl_down(c1.x, 1, 64);
        float n2 = __shfl_down(c2.x, 1, 64);
        int  nam = __shfl_down(amC[0], 1, 64);
        bool valid = true;
        if (lane == 63) {
            if (seg == 31) {
                valid = false;                   // row end: no t+1
            } else {
                const float* pn = base + tb + 512;
                n0 = pn[0]; n1 = pn[TT]; n2 = pn[2 * TT];
                nam = argmax3(n0, n1, n2);
            }
        }
        if (valid) {
            const float d0 = n0 - c0.w, d1 = n1 - c1.w, d2 = n2 - c2.w;
            ss  += d0 * d0 + d1 * d1 + d2 * d2;
            cnt += (0x8C >> (3 * amC[3] + nam)) & 1;
        }
    }

    // wave64 shuffle reduction
    float fcnt = (float)cnt;
#pragma unroll
    for (int off = 32; off > 0; off >>= 1) {
        nll  += __shfl_down(nll,  off, 64);
        ss   += __shfl_down(ss,   off, 64);
        fcnt += __shfl_down(fcnt, off, 64);
    }

    __shared__ float s_nll[4], s_ss[4], s_cnt[4];
    const int wave = threadIdx.x >> 6;
    if (lane == 0) { s_nll[wave] = nll; s_ss[wave] = ss; s_cnt[wave] = fcnt; }
    __syncthreads();
    if (threadIdx.x == 0) {
        partials[blockIdx.x]            = s_nll[0] + s_nll[1] + s_nll[2] + s_nll[3];
        partials[NBLK + blockIdx.x]     = s_ss[0]  + s_ss[1]  + s_ss[2]  + s_ss[3];
        partials[2 * NBLK + blockIdx.x] = s_cnt[0] + s_cnt[1] + s_cnt[2] + s_cnt[3];
    }
}

__global__ __launch_bounds__(256) void ce_trans_final(const float* __restrict__ partials,
                                                      float* __restrict__ out) {
    float sn = 0.f, st = 0.f, sc = 0.f;
    // each stream: 4096 floats = 1024 float4; 256 threads x 4 float4
#pragma unroll
    for (int k = 0; k < 4; ++k) {
        const int i = k * 256 + threadIdx.x;
        const v4f n4 = *((const v4f*)partials + i);
        const v4f s4 = *((const v4f*)partials + 1024 + i);
        const v4f c4 = *((const v4f*)partials + 2048 + i);
        sn += n4.x + n4.y + n4.z + n4.w;
        st += s4.x + s4.y + s4.z + s4.w;
        sc += c4.x + c4.y + c4.z + c4.w;
    }
#pragma unroll
    for (int off = 32; off > 0; off >>= 1) {
        sn += __shfl_down(sn, off, 64);
        st += __shfl_down(st, off, 64);
        sc += __shfl_down(sc, off, 64);
    }
    __shared__ float s_n[4], s_s[4], s_c[4];
    const int wave = threadIdx.x >> 6;
    if ((threadIdx.x & 63) == 0) { s_n[wave] = sn; s_s[wave] = st; s_c[wave] = sc; }
    __syncthreads();
    if (threadIdx.x == 0) {
        const float tn = s_n[0] + s_n[1] + s_n[2] + s_n[3];
        const float ts = s_s[0] + s_s[1] + s_s[2] + s_s[3];
        const float tc = s_c[0] + s_c[1] + s_c[2] + s_c[3];
        const float ce = tn / 8388608.0f;              // B*T
        const float sm = 0.01f * (ts / 25164288.0f);   // B*C*(T-1)
        const float tp = (tc > 0.5f) ? 0.1f : 0.0f;    // all table values are 1 => sum/count == 1
        out[0] = ce + sm + tp;
    }
}

extern "C" void kernel_launch(void* const* d_in, const int* in_sizes, int n_in,
                              void* d_out, int out_size, void* d_ws, size_t ws_size,
                              hipStream_t stream) {
    const float* logits = (const float*)d_in[0];
    const int*   labels = (const int*)d_in[1];
    float* out      = (float*)d_out;
    float* partials = (float*)d_ws;   // 3 * 4096 floats = 48 KB

    ce_trans_main<<<NBLK, 256, 0, stream>>>(logits, labels, partials);
    ce_trans_final<<<1, 256, 0, stream>>>(partials, out);
}